// Round 19
// baseline (139.626 us; speedup 1.0000x reference)
//
#include <hip/hip_runtime.h>
#include <cstddef>

#define NEDGES   800000
#define NRAD     32
#define MAXZ     100
#define NGRP     (NEDGES / 16)                   // 50000 groups of 16 edges
#define NBATCH   (NGRP / 2)                      // 25000 batches of 2 groups
#define NBLK     768                             // persistent, 3 blocks/CU (LDS cap)
#define WPB      4                               // waves per 256-thr block
#define NWAVE    (NBLK * WPB)                    // 3072
// ws layout (float units)
#define PT_OFF   0                               // 200*128 u16 packed = 12800 floats
#define FB_OFF   12800                           // 4096 u16 = 2048 floats
#define ZP_OFF   (FB_OFF + 2048)                 // 800000 ushort

typedef __attribute__((ext_vector_type(8))) short bf16x8;
typedef __attribute__((ext_vector_type(4))) float f32x4;
typedef __attribute__((ext_vector_type(4))) unsigned int u32x4;

__device__ inline unsigned short f2bf(float f) {            // RTNE f32->bf16
    unsigned u = __float_as_uint(f);
    u += 0x7FFFu + ((u >> 16) & 1u);
    return (unsigned short)(u >> 16);
}
__device__ inline float bflo(unsigned u) { return __uint_as_float(u << 16); }
__device__ inline float bfhi(unsigned u) { return __uint_as_float(u & 0xFFFF0000u); }
__device__ inline float silu(float v) {
    return v * __builtin_amdgcn_rcpf(1.f + __expf(-v));
}

// ---------------------------------------------------------------------------
// Prep (fused): fold weights, emit packed bf16 tables + MFMA-lane-order FB.
//   PT[z][(d&15)*8 + (d>>4)] = bf16(T[z][d])  (quarter-uniform b128 reads)
//   FB[(g*64 + kh*16 + n16)*8 + j] = bf16(Wc[kh*8+j][16g+n16])
// ---------------------------------------------------------------------------
__global__ __launch_bounds__(128)
void prep_all_kernel(const float* __restrict__ embed_w,
                     const float* __restrict__ w_rbf,
                     const float* __restrict__ w_edge,
                     const float* __restrict__ b_edge,
                     float* __restrict__ ws) {
    const int d = threadIdx.x;
    const int b = blockIdx.x;
    unsigned short* PT = (unsigned short*)(ws + PT_OFF);
    unsigned short* FB = (unsigned short*)(ws + FB_OFF);
    if (b < MAXZ) {
        float a1 = b_edge[d];
        float a2 = 0.f;
        #pragma unroll 8
        for (int k = 0; k < 128; ++k) {
            const float e = embed_w[b * 128 + k];
            a1 = fmaf(e, w_edge[k * 128 + d], a1);
            a2 = fmaf(e, w_edge[(128 + k) * 128 + d], a2);
        }
        const int pc = (d & 15) * 8 + (d >> 4);
        PT[b * 128 + pc]          = f2bf(a1);
        PT[(MAXZ + b) * 128 + pc] = f2bf(a2);
    } else {
        const int q = b - MAXZ;
        float a = 0.f;
        #pragma unroll 8
        for (int m = 0; m < 128; ++m)
            a = fmaf(w_rbf[q * 128 + m], w_edge[(256 + m) * 128 + d], a);
        FB[(((d >> 4) * 64) + ((q >> 3) * 16) + (d & 15)) * 8 + (q & 7)] = f2bf(a);
    }
}

__global__ __launch_bounds__(256)
void zp_kernel(const int* __restrict__ x,
               const int* __restrict__ idx_i,
               const int* __restrict__ idx_j,
               unsigned short* __restrict__ zp) {
    const int e = blockIdx.x * 256 + threadIdx.x;
    zp[e] = (unsigned short)((x[idx_j[e]] << 8) | x[idx_i[e]]);
}

// ---------------------------------------------------------------------------
// Main: R16 structure EXACTLY (best: 135.4 µs — batch-2 register-held
// compute + pure 64-store burst, 256 thr, 12 waves/CU, LDS packed tables,
// depth-1 prefetch) + ONE change: NONTEMPORAL stores in the burst.
// Regime-matched re-test of nt (R7's neutral was a different binder):
// store stream now dominates; nt bypasses L2 write-allocate (the fill-like
// path), attacking the residual per-store ack cost.
// ---------------------------------------------------------------------------
__global__ __launch_bounds__(256, 4)
void edge_kernel(const float* __restrict__ rbf,
                 const unsigned short* __restrict__ zp,
                 const float* __restrict__ ws,
                 float* __restrict__ out) {
    __shared__ unsigned short sT[200 * 128];     // 51200 B packed tables

    const int tid = threadIdx.x;
    {   // stage packed tables: 51200 B = 3200 uint4
        const uint4* __restrict__ src = (const uint4*)(ws + PT_OFF);
        uint4* dst = (uint4*)sT;
        for (int i = tid; i < 3200; i += 256) dst[i] = src[i];
    }
    __syncthreads();

    const int lane = tid & 63;
    const int wid  = tid >> 6;          // 0..3
    const int n16  = lane & 15;
    const int kh   = lane >> 4;

    const bf16x8* __restrict__ FB = (const bf16x8*)(ws + FB_OFF);

    // compute one group into acc (post-silu, ready to store)
    auto COMPG = [&](f32x4 c0, f32x4 c4, ushort4 cz, f32x4* acc) {
        bf16x8 af;
        af[0] = (short)f2bf(c0.x); af[1] = (short)f2bf(c0.y);
        af[2] = (short)f2bf(c0.z); af[3] = (short)f2bf(c0.w);
        af[4] = (short)f2bf(c4.x); af[5] = (short)f2bf(c4.y);
        af[6] = (short)f2bf(c4.z); af[7] = (short)f2bf(c4.w);
        #pragma unroll
        for (int g8 = 0; g8 < 8; ++g8) {
            const bf16x8 bg = FB[g8 * 64 + lane];        // L1-hot reload
            acc[g8] = (f32x4){0.f, 0.f, 0.f, 0.f};
            acc[g8] = __builtin_amdgcn_mfma_f32_16x16x32_bf16(af, bg, acc[g8], 0, 0, 0);
        }
        const unsigned short zv[4] = {cz.x, cz.y, cz.z, cz.w};
        #pragma unroll
        for (int r = 0; r < 4; ++r) {
            const int zj = zv[r] >> 8;
            const int zi = zv[r] & 0xFF;
            const u32x4 q1 = *(const u32x4*)(sT + zj * 128 + n16 * 8);
            const u32x4 q2 = *(const u32x4*)(sT + (MAXZ + zi) * 128 + n16 * 8);
            #pragma unroll
            for (int k = 0; k < 4; ++k) {
                acc[2 * k][r]     = silu(acc[2 * k][r]     + bflo(q1[k]) + bflo(q2[k]));
                acc[2 * k + 1][r] = silu(acc[2 * k + 1][r] + bfhi(q1[k]) + bfhi(q2[k]));
            }
        }
    };

    auto STOREG = [&](int ebase, const f32x4* acc) {
        #pragma unroll
        for (int r = 0; r < 4; ++r) {
            float* __restrict__ op = out + (size_t)(ebase + kh * 4 + r) * 128 + n16;
            #pragma unroll
            for (int k = 0; k < 4; ++k) {
                __builtin_nontemporal_store(acc[2 * k][r],     op + 16 * (2 * k));
                __builtin_nontemporal_store(acc[2 * k + 1][r], op + 16 * (2 * k + 1));
            }
        }
    };

    int bat = blockIdx.x * WPB + wid;

    // prime: current batch's 2 groups (named, no runtime indexing)
    f32x4 cA0a = {0,0,0,0}, cA4a = {0,0,0,0}, cA0b = {0,0,0,0}, cA4b = {0,0,0,0};
    ushort4 cZa = {0,0,0,0}, cZb = {0,0,0,0};
    if (bat < NBATCH) {
        const int eb = bat * 32;
        const f32x4* ar0 = (const f32x4*)(rbf + (size_t)(eb + n16) * NRAD + kh * 8);
        const f32x4* ar1 = (const f32x4*)(rbf + (size_t)(eb + 16 + n16) * NRAD + kh * 8);
        cA0a = ar0[0]; cA4a = ar0[1]; cZa = *(const ushort4*)(zp + eb + kh * 4);
        cA0b = ar1[0]; cA4b = ar1[1]; cZb = *(const ushort4*)(zp + eb + 16 + kh * 4);
    }

    while (bat < NBATCH) {
        // prefetch next batch
        f32x4 nA0a = {0,0,0,0}, nA4a = {0,0,0,0}, nA0b = {0,0,0,0}, nA4b = {0,0,0,0};
        ushort4 nZa = {0,0,0,0}, nZb = {0,0,0,0};
        const int nb = bat + NWAVE;
        if (nb < NBATCH) {
            const int eb = nb * 32;
            const f32x4* ar0 = (const f32x4*)(rbf + (size_t)(eb + n16) * NRAD + kh * 8);
            const f32x4* ar1 = (const f32x4*)(rbf + (size_t)(eb + 16 + n16) * NRAD + kh * 8);
            nA0a = ar0[0]; nA4a = ar0[1]; nZa = *(const ushort4*)(zp + eb + kh * 4);
            nA0b = ar1[0]; nA4b = ar1[1]; nZb = *(const ushort4*)(zp + eb + 16 + kh * 4);
        }

        // compute both groups fully into registers (no stores yet)
        f32x4 accA[8], accB[8];
        COMPG(cA0a, cA4a, cZa, accA);
        COMPG(cA0b, cA4b, cZb, accB);

        // pure store burst: 64 back-to-back nt stores, no intervening waits
        const int e0 = bat * 32;
        STOREG(e0,      accA);
        STOREG(e0 + 16, accB);

        cA0a = nA0a; cA4a = nA4a; cZa = nZa;
        cA0b = nA0b; cA4b = nA4b; cZb = nZb;
        bat = nb;
    }
}

extern "C" void kernel_launch(void* const* d_in, const int* in_sizes, int n_in,
                              void* d_out, int out_size, void* d_ws, size_t ws_size,
                              hipStream_t stream) {
    const int*   x       = (const int*)d_in[0];
    const float* rbf     = (const float*)d_in[1];
    const int*   idx_i   = (const int*)d_in[2];
    const int*   idx_j   = (const int*)d_in[3];
    const float* embed_w = (const float*)d_in[4];
    const float* w_rbf   = (const float*)d_in[5];
    const float* w_edge  = (const float*)d_in[6];
    const float* b_edge  = (const float*)d_in[7];
    float* out = (float*)d_out;
    float* ws  = (float*)d_ws;
    unsigned short* zp = (unsigned short*)(ws + ZP_OFF);

    prep_all_kernel<<<MAXZ + NRAD, 128, 0, stream>>>(embed_w, w_rbf, w_edge, b_edge, ws);
    zp_kernel<<<NEDGES / 256, 256, 0, stream>>>(x, idx_i, idx_j, zp);
    edge_kernel<<<NBLK, 256, 0, stream>>>(rbf, zp, ws, out);
}

// Round 20
// 135.041 us; speedup vs baseline: 1.0340x; 1.0340x over previous
//
#include <hip/hip_runtime.h>
#include <cstddef>

#define NEDGES   800000
#define NRAD     32
#define MAXZ     100
#define NGRP     (NEDGES / 16)                   // 50000 groups of 16 edges
#define NBATCH   (NGRP / 2)                      // 25000 batches of 2 groups
#define NBLK     768                             // persistent, 3 blocks/CU (LDS cap)
#define WPB      4                               // waves per 256-thr block
#define NWAVE    (NBLK * WPB)                    // 3072
// ws layout (float units)
#define PT_OFF   0                               // 200*128 u16 packed = 12800 floats
#define FB_OFF   12800                           // 4096 u16 = 2048 floats
#define ZP_OFF   (FB_OFF + 2048)                 // 800000 ushort

typedef __attribute__((ext_vector_type(8))) short bf16x8;
typedef __attribute__((ext_vector_type(4))) float f32x4;
typedef __attribute__((ext_vector_type(4))) unsigned int u32x4;

__device__ inline unsigned short f2bf(float f) {            // RTNE f32->bf16
    unsigned u = __float_as_uint(f);
    u += 0x7FFFu + ((u >> 16) & 1u);
    return (unsigned short)(u >> 16);
}
__device__ inline float bflo(unsigned u) { return __uint_as_float(u << 16); }
__device__ inline float bfhi(unsigned u) { return __uint_as_float(u & 0xFFFF0000u); }
__device__ inline float silu(float v) {
    return v * __builtin_amdgcn_rcpf(1.f + __expf(-v));
}

// ---------------------------------------------------------------------------
// Prep (fused): fold weights, emit packed bf16 tables + MFMA-lane-order FB.
//   PT[z][(d&15)*8 + (d>>4)] = bf16(T[z][d])  (quarter-uniform b128 reads)
//   FB[(g*64 + kh*16 + n16)*8 + j] = bf16(Wc[kh*8+j][16g+n16])
// ---------------------------------------------------------------------------
__global__ __launch_bounds__(128)
void prep_all_kernel(const float* __restrict__ embed_w,
                     const float* __restrict__ w_rbf,
                     const float* __restrict__ w_edge,
                     const float* __restrict__ b_edge,
                     float* __restrict__ ws) {
    const int d = threadIdx.x;
    const int b = blockIdx.x;
    unsigned short* PT = (unsigned short*)(ws + PT_OFF);
    unsigned short* FB = (unsigned short*)(ws + FB_OFF);
    if (b < MAXZ) {
        float a1 = b_edge[d];
        float a2 = 0.f;
        #pragma unroll 8
        for (int k = 0; k < 128; ++k) {
            const float e = embed_w[b * 128 + k];
            a1 = fmaf(e, w_edge[k * 128 + d], a1);
            a2 = fmaf(e, w_edge[(128 + k) * 128 + d], a2);
        }
        const int pc = (d & 15) * 8 + (d >> 4);
        PT[b * 128 + pc]          = f2bf(a1);
        PT[(MAXZ + b) * 128 + pc] = f2bf(a2);
    } else {
        const int q = b - MAXZ;
        float a = 0.f;
        #pragma unroll 8
        for (int m = 0; m < 128; ++m)
            a = fmaf(w_rbf[q * 128 + m], w_edge[(256 + m) * 128 + d], a);
        FB[(((d >> 4) * 64) + ((q >> 3) * 16) + (d & 15)) * 8 + (q & 7)] = f2bf(a);
    }
}

__global__ __launch_bounds__(256)
void zp_kernel(const int* __restrict__ x,
               const int* __restrict__ idx_i,
               const int* __restrict__ idx_j,
               unsigned short* __restrict__ zp) {
    const int e = blockIdx.x * 256 + threadIdx.x;
    zp[e] = (unsigned short)((x[idx_j[e]] << 8) | x[idx_i[e]]);
}

// ---------------------------------------------------------------------------
// Main (FINAL = R16, best verified 135.4 µs): batch-2 register-held compute
// + pure 64-store burst per iteration (one load-wait/iter), 256 thr,
// 12 waves/CU, LDS packed bf16 tables (conflict-free b128 quarter-reads),
// depth-1 prefetch placing next loads ahead of the store burst in the VMEM
// FIFO. Confirmed binder history: table-gather L2 lines (fixed R10, +30µs),
// vmcnt-wait events/byte (fixed R16, +22µs). Residual ~1.8x over pure-
// stream BW is mixed read/write DRAM efficiency — structural (R11-R19
// exonerated store shape, nt, occupancy, batching >2).
// ---------------------------------------------------------------------------
__global__ __launch_bounds__(256, 4)
void edge_kernel(const float* __restrict__ rbf,
                 const unsigned short* __restrict__ zp,
                 const float* __restrict__ ws,
                 float* __restrict__ out) {
    __shared__ unsigned short sT[200 * 128];     // 51200 B packed tables

    const int tid = threadIdx.x;
    {   // stage packed tables: 51200 B = 3200 uint4
        const uint4* __restrict__ src = (const uint4*)(ws + PT_OFF);
        uint4* dst = (uint4*)sT;
        for (int i = tid; i < 3200; i += 256) dst[i] = src[i];
    }
    __syncthreads();

    const int lane = tid & 63;
    const int wid  = tid >> 6;          // 0..3
    const int n16  = lane & 15;
    const int kh   = lane >> 4;

    const bf16x8* __restrict__ FB = (const bf16x8*)(ws + FB_OFF);

    // compute one group into acc (post-silu, ready to store)
    auto COMPG = [&](f32x4 c0, f32x4 c4, ushort4 cz, f32x4* acc) {
        bf16x8 af;
        af[0] = (short)f2bf(c0.x); af[1] = (short)f2bf(c0.y);
        af[2] = (short)f2bf(c0.z); af[3] = (short)f2bf(c0.w);
        af[4] = (short)f2bf(c4.x); af[5] = (short)f2bf(c4.y);
        af[6] = (short)f2bf(c4.z); af[7] = (short)f2bf(c4.w);
        #pragma unroll
        for (int g8 = 0; g8 < 8; ++g8) {
            const bf16x8 bg = FB[g8 * 64 + lane];        // L1-hot reload
            acc[g8] = (f32x4){0.f, 0.f, 0.f, 0.f};
            acc[g8] = __builtin_amdgcn_mfma_f32_16x16x32_bf16(af, bg, acc[g8], 0, 0, 0);
        }
        const unsigned short zv[4] = {cz.x, cz.y, cz.z, cz.w};
        #pragma unroll
        for (int r = 0; r < 4; ++r) {
            const int zj = zv[r] >> 8;
            const int zi = zv[r] & 0xFF;
            const u32x4 q1 = *(const u32x4*)(sT + zj * 128 + n16 * 8);
            const u32x4 q2 = *(const u32x4*)(sT + (MAXZ + zi) * 128 + n16 * 8);
            #pragma unroll
            for (int k = 0; k < 4; ++k) {
                acc[2 * k][r]     = silu(acc[2 * k][r]     + bflo(q1[k]) + bflo(q2[k]));
                acc[2 * k + 1][r] = silu(acc[2 * k + 1][r] + bfhi(q1[k]) + bfhi(q2[k]));
            }
        }
    };

    auto STOREG = [&](int ebase, const f32x4* acc) {
        #pragma unroll
        for (int r = 0; r < 4; ++r) {
            float* __restrict__ op = out + (size_t)(ebase + kh * 4 + r) * 128 + n16;
            #pragma unroll
            for (int k = 0; k < 4; ++k) {
                op[16 * (2 * k)]     = acc[2 * k][r];
                op[16 * (2 * k + 1)] = acc[2 * k + 1][r];
            }
        }
    };

    int bat = blockIdx.x * WPB + wid;

    // prime: current batch's 2 groups (named, no runtime indexing)
    f32x4 cA0a = {0,0,0,0}, cA4a = {0,0,0,0}, cA0b = {0,0,0,0}, cA4b = {0,0,0,0};
    ushort4 cZa = {0,0,0,0}, cZb = {0,0,0,0};
    if (bat < NBATCH) {
        const int eb = bat * 32;
        const f32x4* ar0 = (const f32x4*)(rbf + (size_t)(eb + n16) * NRAD + kh * 8);
        const f32x4* ar1 = (const f32x4*)(rbf + (size_t)(eb + 16 + n16) * NRAD + kh * 8);
        cA0a = ar0[0]; cA4a = ar0[1]; cZa = *(const ushort4*)(zp + eb + kh * 4);
        cA0b = ar1[0]; cA4b = ar1[1]; cZb = *(const ushort4*)(zp + eb + 16 + kh * 4);
    }

    while (bat < NBATCH) {
        // prefetch next batch
        f32x4 nA0a = {0,0,0,0}, nA4a = {0,0,0,0}, nA0b = {0,0,0,0}, nA4b = {0,0,0,0};
        ushort4 nZa = {0,0,0,0}, nZb = {0,0,0,0};
        const int nb = bat + NWAVE;
        if (nb < NBATCH) {
            const int eb = nb * 32;
            const f32x4* ar0 = (const f32x4*)(rbf + (size_t)(eb + n16) * NRAD + kh * 8);
            const f32x4* ar1 = (const f32x4*)(rbf + (size_t)(eb + 16 + n16) * NRAD + kh * 8);
            nA0a = ar0[0]; nA4a = ar0[1]; nZa = *(const ushort4*)(zp + eb + kh * 4);
            nA0b = ar1[0]; nA4b = ar1[1]; nZb = *(const ushort4*)(zp + eb + 16 + kh * 4);
        }

        // compute both groups fully into registers (no stores yet)
        f32x4 accA[8], accB[8];
        COMPG(cA0a, cA4a, cZa, accA);
        COMPG(cA0b, cA4b, cZb, accB);

        // pure store burst: 64 back-to-back stores, no intervening waits
        const int e0 = bat * 32;
        STOREG(e0,      accA);
        STOREG(e0 + 16, accB);

        cA0a = nA0a; cA4a = nA4a; cZa = nZa;
        cA0b = nA0b; cA4b = nA4b; cZb = nZb;
        bat = nb;
    }
}

extern "C" void kernel_launch(void* const* d_in, const int* in_sizes, int n_in,
                              void* d_out, int out_size, void* d_ws, size_t ws_size,
                              hipStream_t stream) {
    const int*   x       = (const int*)d_in[0];
    const float* rbf     = (const float*)d_in[1];
    const int*   idx_i   = (const int*)d_in[2];
    const int*   idx_j   = (const int*)d_in[3];
    const float* embed_w = (const float*)d_in[4];
    const float* w_rbf   = (const float*)d_in[5];
    const float* w_edge  = (const float*)d_in[6];
    const float* b_edge  = (const float*)d_in[7];
    float* out = (float*)d_out;
    float* ws  = (float*)d_ws;
    unsigned short* zp = (unsigned short*)(ws + ZP_OFF);

    prep_all_kernel<<<MAXZ + NRAD, 128, 0, stream>>>(embed_w, w_rbf, w_edge, b_edge, ws);
    zp_kernel<<<NEDGES / 256, 256, 0, stream>>>(x, idx_i, idx_j, zp);
    edge_kernel<<<NBLK, 256, 0, stream>>>(rbf, zp, ws, out);
}